// Round 1
// baseline (344.649 us; speedup 1.0000x reference)
//
#include <hip/hip_runtime.h>
#include <math.h>

#define SL   1024
#define BS   64
#define HID  1024
#define D2   2048   // 2*CELL
#define KCAT 3072   // 2*CELL + HID
#define CELL 1024

__device__ __forceinline__ float waveReduceAdd(float v) {
#pragma unroll
    for (int o = 32; o >= 1; o >>= 1) v += __shfl_xor(v, o, 64);
    return v;
}
__device__ __forceinline__ float waveReduceMax(float v) {
#pragma unroll
    for (int o = 32; o >= 1; o >>= 1) v = fmaxf(v, __shfl_xor(v, o, 64));
    return v;
}

// ---------------------------------------------------------------------------
// K1: scores[s,b] = dot(Wh_s[s,b,:], h_t[b,:])  -> scoresT[b*SL + s]
// grid: (SL/16)*BS blocks of 256.  block = 4 waves, each wave 4 s values,
// all waves share one b.  h_t[b] staged in LDS (reused 16x per block).
// ---------------------------------------------------------------------------
__global__ __launch_bounds__(256) void k_scores(const float* __restrict__ Wh,
                                                const float* __restrict__ ht,
                                                float* __restrict__ scoresT) {
    __shared__ float4 lds_ht[HID / 4];
    const int b = blockIdx.x & (BS - 1);
    const int schunk = blockIdx.x >> 6;   // 0..63, 16 s each
    const int t = threadIdx.x;
    lds_ht[t] = reinterpret_cast<const float4*>(ht + (size_t)b * HID)[t];
    __syncthreads();
    const int wave = t >> 6, lane = t & 63;
#pragma unroll
    for (int i = 0; i < 4; ++i) {
        const int s = schunk * 16 + wave * 4 + i;
        const float4* wrow = reinterpret_cast<const float4*>(Wh + ((size_t)s * BS + b) * HID);
        float acc = 0.f;
#pragma unroll
        for (int k = 0; k < 4; ++k) {
            float4 a = wrow[k * 64 + lane];
            float4 h = lds_ht[k * 64 + lane];
            acc = fmaf(a.x, h.x, fmaf(a.y, h.y, fmaf(a.z, h.z, fmaf(a.w, h.w, acc))));
        }
        acc = waveReduceAdd(acc);
        if (lane == 0) scoresT[(size_t)b * SL + s] = acc;
    }
}

// ---------------------------------------------------------------------------
// K2: softmax over s (per b), * mask, renormalize by (masked sum + 1e-8).
// Writes alignT[b*SL + s]  (== alignment.T, the second output).
// grid: BS blocks of 256, 4 elements/thread.
// ---------------------------------------------------------------------------
__global__ __launch_bounds__(256) void k_softmax(const float* __restrict__ scoresT,
                                                 const float* __restrict__ mask,
                                                 float* __restrict__ alignT) {
    const int b = blockIdx.x;
    const int t = threadIdx.x;
    const int wave = t >> 6, lane = t & 63;
    __shared__ float redm[4], reds[4], redms[4];

    float v[4], mk[4];
    float m = -INFINITY;
#pragma unroll
    for (int i = 0; i < 4; ++i) {
        const int s = t + i * 256;
        v[i]  = scoresT[(size_t)b * SL + s];
        mk[i] = mask[(size_t)s * BS + b];
        m = fmaxf(m, v[i]);
    }
    m = waveReduceMax(m);
    if (lane == 0) redm[wave] = m;
    __syncthreads();
    m = fmaxf(fmaxf(redm[0], redm[1]), fmaxf(redm[2], redm[3]));

    float e[4], sum = 0.f, msum = 0.f;
#pragma unroll
    for (int i = 0; i < 4; ++i) {
        e[i] = __expf(v[i] - m);
        sum  += e[i];
        msum += e[i] * mk[i];
    }
    sum  = waveReduceAdd(sum);
    msum = waveReduceAdd(msum);
    if (lane == 0) { reds[wave] = sum; redms[wave] = msum; }
    __syncthreads();
    sum  = reds[0] + reds[1] + reds[2] + reds[3];
    msum = redms[0] + redms[1] + redms[2] + redms[3];

    const float inv   = 1.0f / sum;            // softmax denom
    const float denom = msum * inv + 1e-8f;    // masked sum of softmax + eps
    const float scale = inv / denom;
#pragma unroll
    for (int i = 0; i < 4; ++i) {
        const int s = t + i * 256;
        alignT[(size_t)b * SL + s] = e[i] * mk[i] * scale;
    }
}

// ---------------------------------------------------------------------------
// K3: partial context.  grid (b=BS, dchunk=2, sc=NS), block 256.
// Each block: 1024 floats of d (float4/thread), s_per s-steps accumulated.
// partial[((sc*BS + b))*D2 + d]
// ---------------------------------------------------------------------------
__global__ __launch_bounds__(256) void k_context(const float* __restrict__ hs,
                                                 const float* __restrict__ alignT,
                                                 float* __restrict__ partial,
                                                 int s_per) {
    __shared__ float al[1024];
    const int b = blockIdx.x, dchunk = blockIdx.y, sc = blockIdx.z;
    const int t = threadIdx.x;
    for (int i = t; i < s_per; i += 256)
        al[i] = alignT[(size_t)b * SL + sc * s_per + i];
    __syncthreads();

    const float* base = hs + ((size_t)(sc * s_per) * BS + b) * D2 + dchunk * 1024 + t * 4;
    const size_t stride = (size_t)BS * D2;   // floats per s step
    float4 acc = make_float4(0.f, 0.f, 0.f, 0.f);
    for (int i = 0; i < s_per; i += 4) {
        float4 v0 = *reinterpret_cast<const float4*>(base + (size_t)(i + 0) * stride);
        float4 v1 = *reinterpret_cast<const float4*>(base + (size_t)(i + 1) * stride);
        float4 v2 = *reinterpret_cast<const float4*>(base + (size_t)(i + 2) * stride);
        float4 v3 = *reinterpret_cast<const float4*>(base + (size_t)(i + 3) * stride);
        const float a0 = al[i], a1 = al[i + 1], a2 = al[i + 2], a3 = al[i + 3];
        acc.x = fmaf(a0, v0.x, acc.x); acc.y = fmaf(a0, v0.y, acc.y);
        acc.z = fmaf(a0, v0.z, acc.z); acc.w = fmaf(a0, v0.w, acc.w);
        acc.x = fmaf(a1, v1.x, acc.x); acc.y = fmaf(a1, v1.y, acc.y);
        acc.z = fmaf(a1, v1.z, acc.z); acc.w = fmaf(a1, v1.w, acc.w);
        acc.x = fmaf(a2, v2.x, acc.x); acc.y = fmaf(a2, v2.y, acc.y);
        acc.z = fmaf(a2, v2.z, acc.z); acc.w = fmaf(a2, v2.w, acc.w);
        acc.x = fmaf(a3, v3.x, acc.x); acc.y = fmaf(a3, v3.y, acc.y);
        acc.z = fmaf(a3, v3.z, acc.z); acc.w = fmaf(a3, v3.w, acc.w);
    }
    float* outp = partial + ((size_t)(sc * BS + b)) * D2 + dchunk * 1024 + t * 4;
    *reinterpret_cast<float4*>(outp) = acc;
}

// ---------------------------------------------------------------------------
// K4: reduce NS partials -> context, and build catT[j*BS + b] for j in
// [0,KCAT): j<D2 -> context[b][j], else h_t[b][j-D2].
// grid: (KCAT/256, BS)
// ---------------------------------------------------------------------------
__global__ __launch_bounds__(256) void k_reduce(const float* __restrict__ partial,
                                                const float* __restrict__ ht,
                                                float* __restrict__ catT, int NS) {
    const int j = blockIdx.x * 256 + threadIdx.x;
    const int b = blockIdx.y;
    float v;
    if (j < D2) {
        v = 0.f;
        for (int sc = 0; sc < NS; ++sc)
            v += partial[((size_t)(sc * BS + b)) * D2 + j];
    } else {
        v = ht[(size_t)b * HID + (j - D2)];
    }
    catT[(size_t)j * BS + b] = v;
}

// ---------------------------------------------------------------------------
// K5: h_tilde[b][c] = tanh(bias[c] + sum_j catT[j][b] * W[c][j])
// block 256 = 4 waves; wave handles 4 c for all 64 b (lane = b).
// W addresses are wave-uniform -> scalar loads.
// grid: CELL/16 = 64 blocks.
// ---------------------------------------------------------------------------
__global__ __launch_bounds__(256) void k_out(const float* __restrict__ catT,
                                             const float* __restrict__ W,
                                             const float* __restrict__ bias,
                                             float* __restrict__ out) {
    const int t = threadIdx.x;
    const int wave = t >> 6, lane = t & 63;
    int c0 = blockIdx.x * 16 + wave * 4;
    c0 = __builtin_amdgcn_readfirstlane(c0);
    const float* w0 = W + (size_t)c0 * KCAT;

    float acc0 = 0.f, acc1 = 0.f, acc2 = 0.f, acc3 = 0.f;
#pragma unroll 4
    for (int j = 0; j < KCAT; j += 4) {
        const float a0 = catT[(size_t)(j + 0) * BS + lane];
        const float a1 = catT[(size_t)(j + 1) * BS + lane];
        const float a2 = catT[(size_t)(j + 2) * BS + lane];
        const float a3 = catT[(size_t)(j + 3) * BS + lane];
        float4 w_0 = *reinterpret_cast<const float4*>(w0 + 0 * KCAT + j);
        float4 w_1 = *reinterpret_cast<const float4*>(w0 + 1 * KCAT + j);
        float4 w_2 = *reinterpret_cast<const float4*>(w0 + 2 * KCAT + j);
        float4 w_3 = *reinterpret_cast<const float4*>(w0 + 3 * KCAT + j);
        acc0 = fmaf(a0, w_0.x, fmaf(a1, w_0.y, fmaf(a2, w_0.z, fmaf(a3, w_0.w, acc0))));
        acc1 = fmaf(a0, w_1.x, fmaf(a1, w_1.y, fmaf(a2, w_1.z, fmaf(a3, w_1.w, acc1))));
        acc2 = fmaf(a0, w_2.x, fmaf(a1, w_2.y, fmaf(a2, w_2.z, fmaf(a3, w_2.w, acc2))));
        acc3 = fmaf(a0, w_3.x, fmaf(a1, w_3.y, fmaf(a2, w_3.z, fmaf(a3, w_3.w, acc3))));
    }
    out[(size_t)lane * CELL + c0 + 0] = tanhf(acc0 + bias[c0 + 0]);
    out[(size_t)lane * CELL + c0 + 1] = tanhf(acc1 + bias[c0 + 1]);
    out[(size_t)lane * CELL + c0 + 2] = tanhf(acc2 + bias[c0 + 2]);
    out[(size_t)lane * CELL + c0 + 3] = tanhf(acc3 + bias[c0 + 3]);
}

// ---------------------------------------------------------------------------
extern "C" void kernel_launch(void* const* d_in, const int* in_sizes, int n_in,
                              void* d_out, int out_size, void* d_ws, size_t ws_size,
                              hipStream_t stream) {
    const float* Wh   = (const float*)d_in[0];   // (SL, BS, HID)
    const float* ht   = (const float*)d_in[1];   // (BS, HID)
    const float* mask = (const float*)d_in[2];   // (SL, BS)
    const float* hs   = (const float*)d_in[3];   // (SL, BS, D2)
    const float* W    = (const float*)d_in[4];   // (CELL, KCAT)
    const float* bias = (const float*)d_in[5];   // (CELL,)

    float* out    = (float*)d_out;
    float* htilde = out;                       // (BS, CELL) = 65536 floats
    float* alignT = out + (size_t)BS * CELL;   // (BS, SL)   = 65536 floats

    // workspace layout (floats): scoresT | partial(NS*BS*D2) | catT(KCAT*BS)
    int NS = 8;
    auto need_bytes = [](int ns) -> size_t {
        return ((size_t)BS * SL + (size_t)ns * BS * D2 + (size_t)KCAT * BS) * 4;
    };
    while (NS > 1 && need_bytes(NS) > ws_size) NS >>= 1;

    float* ws      = (float*)d_ws;
    float* scoresT = ws;
    float* partial = ws + (size_t)BS * SL;
    float* catT    = partial + (size_t)NS * BS * D2;

    k_scores<<<(SL / 16) * BS, 256, 0, stream>>>(Wh, ht, scoresT);
    k_softmax<<<BS, 256, 0, stream>>>(scoresT, mask, alignT);
    dim3 g3(BS, 2, NS);
    k_context<<<g3, 256, 0, stream>>>(hs, alignT, partial, SL / NS);
    dim3 g4(KCAT / 256, BS);
    k_reduce<<<g4, 256, 0, stream>>>(partial, ht, catT, NS);
    k_out<<<CELL / 16, 256, 0, stream>>>(catT, W, bias, htilde);
}

// Round 2
// 185.718 us; speedup vs baseline: 1.8558x; 1.8558x over previous
//
#include <hip/hip_runtime.h>
#include <math.h>

#define SL   1024
#define BS   64
#define HID  1024
#define D2   2048   // 2*CELL
#define KCAT 3072   // 2*CELL + HID
#define CELL 1024
#define KS5  16     // K-split factor for the output GEMM
#define JS5  (KCAT / KS5)   // 192 j per slice

__device__ __forceinline__ float waveReduceAdd(float v) {
#pragma unroll
    for (int o = 32; o >= 1; o >>= 1) v += __shfl_xor(v, o, 64);
    return v;
}
__device__ __forceinline__ float waveReduceMax(float v) {
#pragma unroll
    for (int o = 32; o >= 1; o >>= 1) v = fmaxf(v, __shfl_xor(v, o, 64));
    return v;
}

// ---------------------------------------------------------------------------
// K1: scores[s,b] = dot(Wh_s[s,b,:], h_t[b,:])  -> scoresT[b*SL + s]
// grid: (SL/16)*BS blocks of 256.  block = 4 waves, each wave 4 s values,
// all waves share one b.  h_t[b] staged in LDS.  Fully unrolled: 16
// independent float4 global loads in flight per wave.
// ---------------------------------------------------------------------------
__global__ __launch_bounds__(256) void k_scores(const float* __restrict__ Wh,
                                                const float* __restrict__ ht,
                                                float* __restrict__ scoresT) {
    __shared__ float4 lds_ht[HID / 4];
    const int b = blockIdx.x & (BS - 1);
    const int schunk = blockIdx.x >> 6;   // 0..63, 16 s each
    const int t = threadIdx.x;
    lds_ht[t] = reinterpret_cast<const float4*>(ht + (size_t)b * HID)[t];
    __syncthreads();
    const int wave = t >> 6, lane = t & 63;
    const int s0 = schunk * 16 + wave * 4;
    const float4* r0 = reinterpret_cast<const float4*>(Wh + ((size_t)(s0 + 0) * BS + b) * HID) + lane;
    const float4* r1 = reinterpret_cast<const float4*>(Wh + ((size_t)(s0 + 1) * BS + b) * HID) + lane;
    const float4* r2 = reinterpret_cast<const float4*>(Wh + ((size_t)(s0 + 2) * BS + b) * HID) + lane;
    const float4* r3 = reinterpret_cast<const float4*>(Wh + ((size_t)(s0 + 3) * BS + b) * HID) + lane;

    float acc0 = 0.f, acc1 = 0.f, acc2 = 0.f, acc3 = 0.f;
#pragma unroll
    for (int k = 0; k < 4; ++k) {
        const float4 h  = lds_ht[k * 64 + lane];
        const float4 w0 = r0[k * 64];
        const float4 w1 = r1[k * 64];
        const float4 w2 = r2[k * 64];
        const float4 w3 = r3[k * 64];
        acc0 = fmaf(w0.x, h.x, fmaf(w0.y, h.y, fmaf(w0.z, h.z, fmaf(w0.w, h.w, acc0))));
        acc1 = fmaf(w1.x, h.x, fmaf(w1.y, h.y, fmaf(w1.z, h.z, fmaf(w1.w, h.w, acc1))));
        acc2 = fmaf(w2.x, h.x, fmaf(w2.y, h.y, fmaf(w2.z, h.z, fmaf(w2.w, h.w, acc2))));
        acc3 = fmaf(w3.x, h.x, fmaf(w3.y, h.y, fmaf(w3.z, h.z, fmaf(w3.w, h.w, acc3))));
    }
    acc0 = waveReduceAdd(acc0);
    acc1 = waveReduceAdd(acc1);
    acc2 = waveReduceAdd(acc2);
    acc3 = waveReduceAdd(acc3);
    if (lane == 0) {
        float* o = scoresT + (size_t)b * SL + s0;
        o[0] = acc0; o[1] = acc1; o[2] = acc2; o[3] = acc3;
    }
}

// ---------------------------------------------------------------------------
// K2: softmax over s (per b), * mask, renormalize by (masked sum + 1e-8).
// Writes alignT[b*SL + s]  (== alignment.T, the second output).
// ---------------------------------------------------------------------------
__global__ __launch_bounds__(256) void k_softmax(const float* __restrict__ scoresT,
                                                 const float* __restrict__ mask,
                                                 float* __restrict__ alignT) {
    const int b = blockIdx.x;
    const int t = threadIdx.x;
    const int wave = t >> 6, lane = t & 63;
    __shared__ float redm[4], reds[4], redms[4];

    float v[4], mk[4];
    float m = -INFINITY;
#pragma unroll
    for (int i = 0; i < 4; ++i) {
        const int s = t + i * 256;
        v[i]  = scoresT[(size_t)b * SL + s];
        mk[i] = mask[(size_t)s * BS + b];
        m = fmaxf(m, v[i]);
    }
    m = waveReduceMax(m);
    if (lane == 0) redm[wave] = m;
    __syncthreads();
    m = fmaxf(fmaxf(redm[0], redm[1]), fmaxf(redm[2], redm[3]));

    float e[4], sum = 0.f, msum = 0.f;
#pragma unroll
    for (int i = 0; i < 4; ++i) {
        e[i] = __expf(v[i] - m);
        sum  += e[i];
        msum += e[i] * mk[i];
    }
    sum  = waveReduceAdd(sum);
    msum = waveReduceAdd(msum);
    if (lane == 0) { reds[wave] = sum; redms[wave] = msum; }
    __syncthreads();
    sum  = reds[0] + reds[1] + reds[2] + reds[3];
    msum = redms[0] + redms[1] + redms[2] + redms[3];

    const float inv   = 1.0f / sum;            // softmax denom
    const float denom = msum * inv + 1e-8f;    // masked sum of softmax + eps
    const float scale = inv / denom;
#pragma unroll
    for (int i = 0; i < 4; ++i) {
        const int s = t + i * 256;
        alignT[(size_t)b * SL + s] = e[i] * mk[i] * scale;
    }
}

// ---------------------------------------------------------------------------
// K3: partial context.  grid (b=BS, dchunk=2, sc=NS), block 256.
// Each block: 1024 floats of d (float4/thread), s_per s-steps accumulated.
// Unroll-8, two accumulator chains -> 8 loads in flight.
// ---------------------------------------------------------------------------
__global__ __launch_bounds__(256) void k_context(const float* __restrict__ hs,
                                                 const float* __restrict__ alignT,
                                                 float* __restrict__ partial,
                                                 int s_per) {
    __shared__ float al[1024];
    const int b = blockIdx.x, dchunk = blockIdx.y, sc = blockIdx.z;
    const int t = threadIdx.x;
    for (int i = t; i < s_per; i += 256)
        al[i] = alignT[(size_t)b * SL + sc * s_per + i];
    __syncthreads();

    const float* base = hs + ((size_t)(sc * s_per) * BS + b) * D2 + dchunk * 1024 + t * 4;
    const size_t stride = (size_t)BS * D2;   // floats per s step
    float4 accA = make_float4(0.f, 0.f, 0.f, 0.f);
    float4 accB = make_float4(0.f, 0.f, 0.f, 0.f);
    for (int i = 0; i < s_per; i += 8) {
        float4 v0 = *reinterpret_cast<const float4*>(base + (size_t)(i + 0) * stride);
        float4 v1 = *reinterpret_cast<const float4*>(base + (size_t)(i + 1) * stride);
        float4 v2 = *reinterpret_cast<const float4*>(base + (size_t)(i + 2) * stride);
        float4 v3 = *reinterpret_cast<const float4*>(base + (size_t)(i + 3) * stride);
        float4 v4 = *reinterpret_cast<const float4*>(base + (size_t)(i + 4) * stride);
        float4 v5 = *reinterpret_cast<const float4*>(base + (size_t)(i + 5) * stride);
        float4 v6 = *reinterpret_cast<const float4*>(base + (size_t)(i + 6) * stride);
        float4 v7 = *reinterpret_cast<const float4*>(base + (size_t)(i + 7) * stride);
        const float a0 = al[i + 0], a1 = al[i + 1], a2 = al[i + 2], a3 = al[i + 3];
        const float a4 = al[i + 4], a5 = al[i + 5], a6 = al[i + 6], a7 = al[i + 7];
        accA.x = fmaf(a0, v0.x, accA.x); accA.y = fmaf(a0, v0.y, accA.y);
        accA.z = fmaf(a0, v0.z, accA.z); accA.w = fmaf(a0, v0.w, accA.w);
        accA.x = fmaf(a1, v1.x, accA.x); accA.y = fmaf(a1, v1.y, accA.y);
        accA.z = fmaf(a1, v1.z, accA.z); accA.w = fmaf(a1, v1.w, accA.w);
        accA.x = fmaf(a2, v2.x, accA.x); accA.y = fmaf(a2, v2.y, accA.y);
        accA.z = fmaf(a2, v2.z, accA.z); accA.w = fmaf(a2, v2.w, accA.w);
        accA.x = fmaf(a3, v3.x, accA.x); accA.y = fmaf(a3, v3.y, accA.y);
        accA.z = fmaf(a3, v3.z, accA.z); accA.w = fmaf(a3, v3.w, accA.w);
        accB.x = fmaf(a4, v4.x, accB.x); accB.y = fmaf(a4, v4.y, accB.y);
        accB.z = fmaf(a4, v4.z, accB.z); accB.w = fmaf(a4, v4.w, accB.w);
        accB.x = fmaf(a5, v5.x, accB.x); accB.y = fmaf(a5, v5.y, accB.y);
        accB.z = fmaf(a5, v5.z, accB.z); accB.w = fmaf(a5, v5.w, accB.w);
        accB.x = fmaf(a6, v6.x, accB.x); accB.y = fmaf(a6, v6.y, accB.y);
        accB.z = fmaf(a6, v6.z, accB.z); accB.w = fmaf(a6, v6.w, accB.w);
        accB.x = fmaf(a7, v7.x, accB.x); accB.y = fmaf(a7, v7.y, accB.y);
        accB.z = fmaf(a7, v7.z, accB.z); accB.w = fmaf(a7, v7.w, accB.w);
    }
    float4 acc = make_float4(accA.x + accB.x, accA.y + accB.y,
                             accA.z + accB.z, accA.w + accB.w);
    float* outp = partial + ((size_t)(sc * BS + b)) * D2 + dchunk * 1024 + t * 4;
    *reinterpret_cast<float4*>(outp) = acc;
}

// ---------------------------------------------------------------------------
// K4: reduce NS partials -> context, and build catT[j*BS + b] for j in
// [0,KCAT): j<D2 -> context[b][j], else h_t[b][j-D2].
// ---------------------------------------------------------------------------
__global__ __launch_bounds__(256) void k_reduce(const float* __restrict__ partial,
                                                const float* __restrict__ ht,
                                                float* __restrict__ catT, int NS) {
    const int j = blockIdx.x * 256 + threadIdx.x;
    const int b = blockIdx.y;
    float v;
    if (j < D2) {
        v = 0.f;
        for (int sc = 0; sc < NS; ++sc)
            v += partial[((size_t)(sc * BS + b)) * D2 + j];
    } else {
        v = ht[(size_t)b * HID + (j - D2)];
    }
    catT[(size_t)j * BS + b] = v;
}

// ---------------------------------------------------------------------------
// K5: split-K GEMM partials.  grid (CELL/16, KS5), block 256 = 4 waves.
// wave handles 4 c rows over a K-slice of JS5=192; lane = b.
// part[(ks*CELL + c)*BS + b]
// ---------------------------------------------------------------------------
__global__ __launch_bounds__(256) void k_gemm(const float* __restrict__ catT,
                                              const float* __restrict__ W,
                                              float* __restrict__ part) {
    const int t = threadIdx.x;
    const int wave = t >> 6, lane = t & 63;
    int c0 = blockIdx.x * 16 + wave * 4;
    c0 = __builtin_amdgcn_readfirstlane(c0);
    const int jb = blockIdx.y * JS5;
    const float* w0 = W + (size_t)c0 * KCAT + jb;
    const float* a0p = catT + (size_t)jb * BS + lane;

    float acc0 = 0.f, acc1 = 0.f, acc2 = 0.f, acc3 = 0.f;
#pragma unroll 2
    for (int j = 0; j < JS5; j += 4) {
        const float a0 = a0p[(size_t)(j + 0) * BS];
        const float a1 = a0p[(size_t)(j + 1) * BS];
        const float a2 = a0p[(size_t)(j + 2) * BS];
        const float a3 = a0p[(size_t)(j + 3) * BS];
        float4 w_0 = *reinterpret_cast<const float4*>(w0 + 0 * KCAT + j);
        float4 w_1 = *reinterpret_cast<const float4*>(w0 + 1 * KCAT + j);
        float4 w_2 = *reinterpret_cast<const float4*>(w0 + 2 * KCAT + j);
        float4 w_3 = *reinterpret_cast<const float4*>(w0 + 3 * KCAT + j);
        acc0 = fmaf(a0, w_0.x, fmaf(a1, w_0.y, fmaf(a2, w_0.z, fmaf(a3, w_0.w, acc0))));
        acc1 = fmaf(a0, w_1.x, fmaf(a1, w_1.y, fmaf(a2, w_1.z, fmaf(a3, w_1.w, acc1))));
        acc2 = fmaf(a0, w_2.x, fmaf(a1, w_2.y, fmaf(a2, w_2.z, fmaf(a3, w_2.w, acc2))));
        acc3 = fmaf(a0, w_3.x, fmaf(a1, w_3.y, fmaf(a2, w_3.z, fmaf(a3, w_3.w, acc3))));
    }
    float* p = part + ((size_t)blockIdx.y * CELL + c0) * BS + lane;
    p[0 * BS] = acc0; p[1 * BS] = acc1; p[2 * BS] = acc2; p[3 * BS] = acc3;
}

// ---------------------------------------------------------------------------
// K6: out[b][c] = tanh(bias[c] + sum_ks part[ks][c][b])
// grid 256 blocks of 256; coalesced reads (b fastest), scattered 4B writes
// (only 256 KB -> negligible).
// ---------------------------------------------------------------------------
__global__ __launch_bounds__(256) void k_finish(const float* __restrict__ part,
                                                const float* __restrict__ bias,
                                                float* __restrict__ out) {
    const int idx = blockIdx.x * 256 + threadIdx.x;   // 0..CELL*BS-1
    const int c = idx >> 6, b = idx & 63;
    float s = bias[c];
#pragma unroll
    for (int ks = 0; ks < KS5; ++ks)
        s += part[(size_t)ks * CELL * BS + idx];
    out[(size_t)b * CELL + c] = tanhf(s);
}

// ---------------------------------------------------------------------------
extern "C" void kernel_launch(void* const* d_in, const int* in_sizes, int n_in,
                              void* d_out, int out_size, void* d_ws, size_t ws_size,
                              hipStream_t stream) {
    const float* Wh   = (const float*)d_in[0];   // (SL, BS, HID)
    const float* ht   = (const float*)d_in[1];   // (BS, HID)
    const float* mask = (const float*)d_in[2];   // (SL, BS)
    const float* hs   = (const float*)d_in[3];   // (SL, BS, D2)
    const float* W    = (const float*)d_in[4];   // (CELL, KCAT)
    const float* bias = (const float*)d_in[5];   // (CELL,)

    float* out    = (float*)d_out;
    float* htilde = out;                       // (BS, CELL) = 65536 floats
    float* alignT = out + (size_t)BS * CELL;   // (BS, SL)   = 65536 floats

    // workspace layout (floats):
    //   scoresT | partial(NS*BS*D2) | catT(KCAT*BS) | part5(KS5*CELL*BS)
    int NS = 16;
    auto need_bytes = [](int ns) -> size_t {
        return ((size_t)BS * SL + (size_t)ns * BS * D2 + (size_t)KCAT * BS +
                (size_t)KS5 * CELL * BS) * 4;
    };
    while (NS > 1 && need_bytes(NS) > ws_size) NS >>= 1;

    float* ws      = (float*)d_ws;
    float* scoresT = ws;
    float* partial = ws + (size_t)BS * SL;
    float* catT    = partial + (size_t)NS * BS * D2;
    float* part5   = catT + (size_t)KCAT * BS;

    k_scores<<<(SL / 16) * BS, 256, 0, stream>>>(Wh, ht, scoresT);
    k_softmax<<<BS, 256, 0, stream>>>(scoresT, mask, alignT);
    dim3 g3(BS, 2, NS);
    k_context<<<g3, 256, 0, stream>>>(hs, alignT, partial, SL / NS);
    dim3 g4(KCAT / 256, BS);
    k_reduce<<<g4, 256, 0, stream>>>(partial, ht, catT, NS);
    dim3 g5(CELL / 16, KS5);
    k_gemm<<<g5, 256, 0, stream>>>(catT, W, part5);
    k_finish<<<(CELL * BS) / 256, 256, 0, stream>>>(part5, bias, htilde);
}

// Round 4
// 182.035 us; speedup vs baseline: 1.8933x; 1.0202x over previous
//
#include <hip/hip_runtime.h>
#include <math.h>

#define SL   1024
#define BS   64
#define HID  1024
#define D2   2048   // 2*CELL
#define KCAT 3072   // 2*CELL + HID
#define CELL 1024
#define KS5  16     // K-split factor for the output GEMM
#define JS5  (KCAT / KS5)   // 192 j per slice

typedef float vfloat4 __attribute__((ext_vector_type(4)));

__device__ __forceinline__ float4 ntload(const float4* p) {
    vfloat4 v = __builtin_nontemporal_load(reinterpret_cast<const vfloat4*>(p));
    return make_float4(v.x, v.y, v.z, v.w);
}

__device__ __forceinline__ float waveReduceAdd(float v) {
#pragma unroll
    for (int o = 32; o >= 1; o >>= 1) v += __shfl_xor(v, o, 64);
    return v;
}
__device__ __forceinline__ float waveReduceMax(float v) {
#pragma unroll
    for (int o = 32; o >= 1; o >>= 1) v = fmaxf(v, __shfl_xor(v, o, 64));
    return v;
}

// ---------------------------------------------------------------------------
// K1: scores[s,b] = dot(Wh_s[s,b,:], h_t[b,:])  -> scoresT[b*SL + s]
// grid: (SL/16)*BS blocks of 256.  block = 4 waves, each wave 4 s values,
// all waves share one b.  h_t[b] staged in LDS.  16 nontemporal float4
// loads in flight per wave.
// ---------------------------------------------------------------------------
__global__ __launch_bounds__(256) void k_scores(const float* __restrict__ Wh,
                                                const float* __restrict__ ht,
                                                float* __restrict__ scoresT) {
    __shared__ float4 lds_ht[HID / 4];
    const int b = blockIdx.x & (BS - 1);
    const int schunk = blockIdx.x >> 6;   // 0..63, 16 s each
    const int t = threadIdx.x;
    lds_ht[t] = reinterpret_cast<const float4*>(ht + (size_t)b * HID)[t];
    __syncthreads();
    const int wave = t >> 6, lane = t & 63;
    const int s0 = schunk * 16 + wave * 4;
    const float4* r0 = reinterpret_cast<const float4*>(Wh + ((size_t)(s0 + 0) * BS + b) * HID) + lane;
    const float4* r1 = reinterpret_cast<const float4*>(Wh + ((size_t)(s0 + 1) * BS + b) * HID) + lane;
    const float4* r2 = reinterpret_cast<const float4*>(Wh + ((size_t)(s0 + 2) * BS + b) * HID) + lane;
    const float4* r3 = reinterpret_cast<const float4*>(Wh + ((size_t)(s0 + 3) * BS + b) * HID) + lane;

    float4 w[4][4];
#pragma unroll
    for (int k = 0; k < 4; ++k) {
        w[0][k] = ntload(r0 + k * 64);
        w[1][k] = ntload(r1 + k * 64);
        w[2][k] = ntload(r2 + k * 64);
        w[3][k] = ntload(r3 + k * 64);
    }
    float acc0 = 0.f, acc1 = 0.f, acc2 = 0.f, acc3 = 0.f;
#pragma unroll
    for (int k = 0; k < 4; ++k) {
        const float4 h = lds_ht[k * 64 + lane];
        acc0 = fmaf(w[0][k].x, h.x, fmaf(w[0][k].y, h.y, fmaf(w[0][k].z, h.z, fmaf(w[0][k].w, h.w, acc0))));
        acc1 = fmaf(w[1][k].x, h.x, fmaf(w[1][k].y, h.y, fmaf(w[1][k].z, h.z, fmaf(w[1][k].w, h.w, acc1))));
        acc2 = fmaf(w[2][k].x, h.x, fmaf(w[2][k].y, h.y, fmaf(w[2][k].z, h.z, fmaf(w[2][k].w, h.w, acc2))));
        acc3 = fmaf(w[3][k].x, h.x, fmaf(w[3][k].y, h.y, fmaf(w[3][k].z, h.z, fmaf(w[3][k].w, h.w, acc3))));
    }
    acc0 = waveReduceAdd(acc0);
    acc1 = waveReduceAdd(acc1);
    acc2 = waveReduceAdd(acc2);
    acc3 = waveReduceAdd(acc3);
    if (lane == 0) {
        float* o = scoresT + (size_t)b * SL + s0;
        o[0] = acc0; o[1] = acc1; o[2] = acc2; o[3] = acc3;
    }
}

// ---------------------------------------------------------------------------
// K2: softmax over s (per b), * mask, renormalize by (masked sum + 1e-8).
// Writes alignT[b*SL + s]  (== alignment.T, the second output).
// ---------------------------------------------------------------------------
__global__ __launch_bounds__(256) void k_softmax(const float* __restrict__ scoresT,
                                                 const float* __restrict__ mask,
                                                 float* __restrict__ alignT) {
    const int b = blockIdx.x;
    const int t = threadIdx.x;
    const int wave = t >> 6, lane = t & 63;
    __shared__ float redm[4], reds[4], redms[4];

    float v[4], mk[4];
    float m = -INFINITY;
#pragma unroll
    for (int i = 0; i < 4; ++i) {
        const int s = t + i * 256;
        v[i]  = scoresT[(size_t)b * SL + s];
        mk[i] = mask[(size_t)s * BS + b];
        m = fmaxf(m, v[i]);
    }
    m = waveReduceMax(m);
    if (lane == 0) redm[wave] = m;
    __syncthreads();
    m = fmaxf(fmaxf(redm[0], redm[1]), fmaxf(redm[2], redm[3]));

    float e[4], sum = 0.f, msum = 0.f;
#pragma unroll
    for (int i = 0; i < 4; ++i) {
        e[i] = __expf(v[i] - m);
        sum  += e[i];
        msum += e[i] * mk[i];
    }
    sum  = waveReduceAdd(sum);
    msum = waveReduceAdd(msum);
    if (lane == 0) { reds[wave] = sum; redms[wave] = msum; }
    __syncthreads();
    sum  = reds[0] + reds[1] + reds[2] + reds[3];
    msum = redms[0] + redms[1] + redms[2] + redms[3];

    const float inv   = 1.0f / sum;            // softmax denom
    const float denom = msum * inv + 1e-8f;    // masked sum of softmax + eps
    const float scale = inv / denom;
#pragma unroll
    for (int i = 0; i < 4; ++i) {
        const int s = t + i * 256;
        alignT[(size_t)b * SL + s] = e[i] * mk[i] * scale;
    }
}

// ---------------------------------------------------------------------------
// K3: partial context.  grid (b=BS, sc=NS), block 256.
// Block owns the FULL D2 row: 8 floats (2 float4) per thread.
// Unroll-8 s-steps -> 16 nontemporal float4 loads (256 B/lane) in flight.
// partial[(sc*BS + b)*D2 + d]
// ---------------------------------------------------------------------------
__global__ __launch_bounds__(256) void k_context(const float* __restrict__ hs,
                                                 const float* __restrict__ alignT,
                                                 float* __restrict__ partial,
                                                 int s_per) {
    __shared__ float al[SL];
    const int b = blockIdx.x, sc = blockIdx.y;
    const int t = threadIdx.x;
    for (int i = t; i < s_per; i += 256)
        al[i] = alignT[(size_t)b * SL + sc * s_per + i];
    __syncthreads();

    const float* base = hs + ((size_t)(sc * s_per) * BS + b) * D2 + t * 8;
    const size_t stride = (size_t)BS * D2;   // floats per s step
    float4 accA0 = make_float4(0.f, 0.f, 0.f, 0.f);
    float4 accA1 = make_float4(0.f, 0.f, 0.f, 0.f);
    float4 accB0 = make_float4(0.f, 0.f, 0.f, 0.f);
    float4 accB1 = make_float4(0.f, 0.f, 0.f, 0.f);
    for (int i = 0; i < s_per; i += 8) {
        float4 v[8][2];
#pragma unroll
        for (int j = 0; j < 8; ++j) {
            const float4* p = reinterpret_cast<const float4*>(base + (size_t)(i + j) * stride);
            v[j][0] = ntload(p);
            v[j][1] = ntload(p + 1);
        }
#pragma unroll
        for (int j = 0; j < 8; ++j) {
            const float a = al[i + j];
            float4* acc0 = (j & 1) ? &accB0 : &accA0;
            float4* acc1 = (j & 1) ? &accB1 : &accA1;
            acc0->x = fmaf(a, v[j][0].x, acc0->x);
            acc0->y = fmaf(a, v[j][0].y, acc0->y);
            acc0->z = fmaf(a, v[j][0].z, acc0->z);
            acc0->w = fmaf(a, v[j][0].w, acc0->w);
            acc1->x = fmaf(a, v[j][1].x, acc1->x);
            acc1->y = fmaf(a, v[j][1].y, acc1->y);
            acc1->z = fmaf(a, v[j][1].z, acc1->z);
            acc1->w = fmaf(a, v[j][1].w, acc1->w);
        }
    }
    float4 o0 = make_float4(accA0.x + accB0.x, accA0.y + accB0.y,
                            accA0.z + accB0.z, accA0.w + accB0.w);
    float4 o1 = make_float4(accA1.x + accB1.x, accA1.y + accB1.y,
                            accA1.z + accB1.z, accA1.w + accB1.w);
    float* outp = partial + ((size_t)(sc * BS + b)) * D2 + t * 8;
    reinterpret_cast<float4*>(outp)[0] = o0;
    reinterpret_cast<float4*>(outp)[1] = o1;
}

// ---------------------------------------------------------------------------
// K4: reduce NS partials -> context, and build catT[j*BS + b] for j in
// [0,KCAT): j<D2 -> context[b][j], else h_t[b][j-D2].  float4 reads.
// grid: (KCAT/4/256, BS)
// ---------------------------------------------------------------------------
__global__ __launch_bounds__(256) void k_reduce(const float* __restrict__ partial,
                                                const float* __restrict__ ht,
                                                float* __restrict__ catT, int NS) {
    const int j0 = (blockIdx.x * 256 + threadIdx.x) * 4;
    const int b = blockIdx.y;
    float4 v;
    if (j0 < D2) {
        v = make_float4(0.f, 0.f, 0.f, 0.f);
        for (int sc = 0; sc < NS; ++sc) {
            float4 p = *reinterpret_cast<const float4*>(
                partial + ((size_t)(sc * BS + b)) * D2 + j0);
            v.x += p.x; v.y += p.y; v.z += p.z; v.w += p.w;
        }
    } else {
        v = *reinterpret_cast<const float4*>(ht + (size_t)b * HID + (j0 - D2));
    }
    catT[(size_t)(j0 + 0) * BS + b] = v.x;
    catT[(size_t)(j0 + 1) * BS + b] = v.y;
    catT[(size_t)(j0 + 2) * BS + b] = v.z;
    catT[(size_t)(j0 + 3) * BS + b] = v.w;
}

// ---------------------------------------------------------------------------
// K5: split-K GEMM partials.  grid (CELL/16, KS5), block 256 = 4 waves.
// wave handles 4 c rows over a K-slice of JS5=192; lane = b.
// part[(ks*CELL + c)*BS + b]
// ---------------------------------------------------------------------------
__global__ __launch_bounds__(256) void k_gemm(const float* __restrict__ catT,
                                              const float* __restrict__ W,
                                              float* __restrict__ part) {
    const int t = threadIdx.x;
    const int wave = t >> 6, lane = t & 63;
    int c0 = blockIdx.x * 16 + wave * 4;
    c0 = __builtin_amdgcn_readfirstlane(c0);
    const int jb = blockIdx.y * JS5;
    const float* w0 = W + (size_t)c0 * KCAT + jb;
    const float* a0p = catT + (size_t)jb * BS + lane;

    float acc0 = 0.f, acc1 = 0.f, acc2 = 0.f, acc3 = 0.f;
#pragma unroll 2
    for (int j = 0; j < JS5; j += 4) {
        const float a0 = a0p[(size_t)(j + 0) * BS];
        const float a1 = a0p[(size_t)(j + 1) * BS];
        const float a2 = a0p[(size_t)(j + 2) * BS];
        const float a3 = a0p[(size_t)(j + 3) * BS];
        float4 w_0 = ntload(reinterpret_cast<const float4*>(w0 + 0 * KCAT + j));
        float4 w_1 = ntload(reinterpret_cast<const float4*>(w0 + 1 * KCAT + j));
        float4 w_2 = ntload(reinterpret_cast<const float4*>(w0 + 2 * KCAT + j));
        float4 w_3 = ntload(reinterpret_cast<const float4*>(w0 + 3 * KCAT + j));
        acc0 = fmaf(a0, w_0.x, fmaf(a1, w_0.y, fmaf(a2, w_0.z, fmaf(a3, w_0.w, acc0))));
        acc1 = fmaf(a0, w_1.x, fmaf(a1, w_1.y, fmaf(a2, w_1.z, fmaf(a3, w_1.w, acc1))));
        acc2 = fmaf(a0, w_2.x, fmaf(a1, w_2.y, fmaf(a2, w_2.z, fmaf(a3, w_2.w, acc2))));
        acc3 = fmaf(a0, w_3.x, fmaf(a1, w_3.y, fmaf(a2, w_3.z, fmaf(a3, w_3.w, acc3))));
    }
    float* p = part + ((size_t)blockIdx.y * CELL + c0) * BS + lane;
    p[0 * BS] = acc0; p[1 * BS] = acc1; p[2 * BS] = acc2; p[3 * BS] = acc3;
}

// ---------------------------------------------------------------------------
// K6: out[b][c] = tanh(bias[c] + sum_ks part[ks][c][b])
// ---------------------------------------------------------------------------
__global__ __launch_bounds__(256) void k_finish(const float* __restrict__ part,
                                                const float* __restrict__ bias,
                                                float* __restrict__ out) {
    const int idx = blockIdx.x * 256 + threadIdx.x;   // 0..CELL*BS-1
    const int c = idx >> 6, b = idx & 63;
    float s = bias[c];
#pragma unroll
    for (int ks = 0; ks < KS5; ++ks)
        s += part[(size_t)ks * CELL * BS + idx];
    out[(size_t)b * CELL + c] = tanhf(s);
}

// ---------------------------------------------------------------------------
extern "C" void kernel_launch(void* const* d_in, const int* in_sizes, int n_in,
                              void* d_out, int out_size, void* d_ws, size_t ws_size,
                              hipStream_t stream) {
    const float* Wh   = (const float*)d_in[0];   // (SL, BS, HID)
    const float* ht   = (const float*)d_in[1];   // (BS, HID)
    const float* mask = (const float*)d_in[2];   // (SL, BS)
    const float* hs   = (const float*)d_in[3];   // (SL, BS, D2)
    const float* W    = (const float*)d_in[4];   // (CELL, KCAT)
    const float* bias = (const float*)d_in[5];   // (CELL,)

    float* out    = (float*)d_out;
    float* htilde = out;                       // (BS, CELL) = 65536 floats
    float* alignT = out + (size_t)BS * CELL;   // (BS, SL)   = 65536 floats

    // workspace layout (floats):
    //   scoresT | partial(NS*BS*D2) | catT(KCAT*BS) | part5(KS5*CELL*BS)
    int NS = 16;
    auto need_bytes = [](int ns) -> size_t {
        return ((size_t)BS * SL + (size_t)ns * BS * D2 + (size_t)KCAT * BS +
                (size_t)KS5 * CELL * BS) * 4;
    };
    while (NS > 1 && need_bytes(NS) > ws_size) NS >>= 1;

    float* ws      = (float*)d_ws;
    float* scoresT = ws;
    float* partial = ws + (size_t)BS * SL;
    float* catT    = partial + (size_t)NS * BS * D2;
    float* part5   = catT + (size_t)KCAT * BS;

    k_scores<<<(SL / 16) * BS, 256, 0, stream>>>(Wh, ht, scoresT);
    k_softmax<<<BS, 256, 0, stream>>>(scoresT, mask, alignT);
    dim3 g3(BS, NS);
    k_context<<<g3, 256, 0, stream>>>(hs, alignT, partial, SL / NS);
    dim3 g4(KCAT / 4 / 256, BS);
    k_reduce<<<g4, 256, 0, stream>>>(partial, ht, catT, NS);
    dim3 g5(CELL / 16, KS5);
    k_gemm<<<g5, 256, 0, stream>>>(catT, W, part5);
    k_finish<<<(CELL * BS) / 256, 256, 0, stream>>>(part5, bias, htilde);
}